// Round 10
// baseline (453.135 us; speedup 1.0000x reference)
//
#include <hip/hip_runtime.h>
#include <hip/hip_cooperative_groups.h>
#include <hip/hip_bf16.h>
#include <cstdint>
#include <cstddef>

namespace cg = cooperative_groups;

// Sizes fixed by the reference problem.
#define DMODEL 1024
#define BATCH  4
#define SEQ    4096
#define BSROWS (BATCH*SEQ)     // 16384
#define CHUNK  16
#define NCHUNK (SEQ/CHUNK)     // 256
#define NCH_T  (BATCH*NCHUNK)  // 1024 total chunks

typedef __attribute__((ext_vector_type(8))) short bf16x8;
typedef __attribute__((ext_vector_type(4))) float f32x4;

// ---- helpers ---------------------------------------------------------------

__device__ __forceinline__ unsigned short f2bf(float f) {
  union { float f; uint32_t u; } v; v.f = f;
  uint32_t u = v.u;
  u += 0x7FFFu + ((u >> 16) & 1u);   // round-to-nearest-even
  return (unsigned short)(u >> 16);
}

__device__ __forceinline__ float sigmoid_dev(const float* dp) {
  return 1.0f / (1.0f + expf(-dp[0]));
}

typedef __attribute__((address_space(1))) void void_g;
typedef __attribute__((address_space(3))) void void_l;

__device__ __forceinline__ void gl2lds16(const void* g, void* l) {
  __builtin_amdgcn_global_load_lds((void_g*)g, (void_l*)l, 16, 0, 0);
}

// ---- 64x64-tile NT K-loop (BK=64, XOR-8 swizzle) — phase 2 -----------------
// Ring-3 LDS pipeline, counted vmcnt(4), raw s_barrier. EXACTLY 16 s_barrier
// executions per wave (1 prologue + 14 loop + 1 tail) — echo waves must match.
__device__ __forceinline__ void kloop64(
    const unsigned short* __restrict__ A, const unsigned short* __restrict__ B,
    int m0, int n0, f32x4 acc[2][2],
    unsigned short* As, unsigned short* Bs, int tid) {
  int lane = tid & 63, w = tid >> 6, wm = w & 1, wn = w >> 1;
  int quad = lane >> 4, l16 = lane & 15;
  int r = tid >> 3, cch = tid & 7;
  int g = cch ^ (r & 7);

  auto stage = [&](int t, int slot) {
    int k0 = t * 64;
    unsigned short* dA = As + slot * 4096;
    unsigned short* dB = Bs + slot * 4096;
    gl2lds16(A + (size_t)(m0 + r) * DMODEL + k0 + g * 8,      dA + r * 64 + cch * 8);
    gl2lds16(A + (size_t)(m0 + 32 + r) * DMODEL + k0 + g * 8, dA + (32 + r) * 64 + cch * 8);
    gl2lds16(B + (size_t)(n0 + r) * DMODEL + k0 + g * 8,      dB + r * 64 + cch * 8);
    gl2lds16(B + (size_t)(n0 + 32 + r) * DMODEL + k0 + g * 8, dB + (32 + r) * 64 + cch * 8);
  };
  auto compute = [&](int slot) {
    const bf16x8* Av = (const bf16x8*)(As + slot * 4096);
    const bf16x8* Bv = (const bf16x8*)(Bs + slot * 4096);
    #pragma unroll
    for (int kk = 0; kk < 2; ++kk) {
      bf16x8 af[2], bfr[2];
      #pragma unroll
      for (int i = 0; i < 2; ++i) {
        int rowA = wm * 32 + i * 16 + l16;
        af[i]  = Av[rowA * 8 + ((kk * 4 + quad) ^ (l16 & 7))];
        int rowB = wn * 32 + i * 16 + l16;
        bfr[i] = Bv[rowB * 8 + ((kk * 4 + quad) ^ (l16 & 7))];
      }
      __builtin_amdgcn_s_setprio(1);
      #pragma unroll
      for (int i = 0; i < 2; ++i)
        #pragma unroll
        for (int j = 0; j < 2; ++j)
          acc[i][j] = __builtin_amdgcn_mfma_f32_16x16x32_bf16(af[i], bfr[j], acc[i][j], 0, 0, 0);
      __builtin_amdgcn_s_setprio(0);
    }
  };

  stage(0, 0); stage(1, 1);
  asm volatile("s_waitcnt vmcnt(4)" ::: "memory");
  __builtin_amdgcn_s_barrier();                         // B1
  asm volatile("" ::: "memory");
  int cur = 0;
  for (int t = 0; t < 14; ++t) {
    int ns = cur + 2; if (ns >= 3) ns -= 3;
    stage(t + 2, ns);
    compute(cur);
    asm volatile("s_waitcnt vmcnt(4)" ::: "memory");
    __builtin_amdgcn_s_barrier();                       // B2..B15
    asm volatile("" ::: "memory");
    cur = (cur == 2) ? 0 : cur + 1;
  }
  compute(cur);                                        // tile 14
  asm volatile("s_waitcnt vmcnt(0)" ::: "memory");
  __builtin_amdgcn_s_barrier();                         // B16
  asm volatile("" ::: "memory");
  cur = (cur == 2) ? 0 : cur + 1;
  compute(cur);                                        // tile 15
}

// ---- single-chunk local scan (phase 1), 4-deep prefetch --------------------
__device__ __forceinline__ void scan_chunk(
    int ch, int ltid, float decay,
    const float* __restrict__ x, const float* __restrict__ mask,
    unsigned short* __restrict__ hv, float* __restrict__ carry,
    float* __restrict__ lbeta, float* __restrict__ cbeta) {
  int b = ch >> 8, c = ch & 255;
  int base = b * SEQ + c * CHUNK;
  const float4* xp = (const float4*)(x + (size_t)base * DMODEL);
  const float4* mp4 = (const float4*)(mask + base);
  float mreg[16];
  #pragma unroll
  for (int q = 0; q < 4; ++q) {
    float4 t = mp4[q];
    mreg[q * 4 + 0] = t.x; mreg[q * 4 + 1] = t.y;
    mreg[q * 4 + 2] = t.z; mreg[q * 4 + 3] = t.w;
  }
  // beta scan (register-only predicated unroll; lanes ltid<16 hold results)
  {
    float hb = 0.f;
    #pragma unroll
    for (int i = 0; i < 16; ++i) {
      float nv = decay * hb + mreg[i];
      hb = (ltid >= i) ? nv : hb;
    }
    if (ltid < 16) {
      lbeta[base + ltid] = hb;
      if (ltid == 15) cbeta[ch] = hb;
    }
  }
  float4 x0 = xp[ltid], x1 = xp[256 + ltid], x2 = xp[512 + ltid], x3 = xp[768 + ltid];
  float4 h = make_float4(0.f, 0.f, 0.f, 0.f);
  #pragma unroll
  for (int s = 0; s < CHUNK; ++s) {
    float4 cur = x0; x0 = x1; x1 = x2; x2 = x3;
    if (s + 4 < CHUNK) x3 = xp[(size_t)(s + 4) * 256 + ltid];
    float m = mreg[s];
    h.x = decay * h.x + m * cur.x;
    h.y = decay * h.y + m * cur.y;
    h.z = decay * h.z + m * cur.z;
    h.w = decay * h.w + m * cur.w;
    ushort4 o;
    o.x = f2bf(h.x); o.y = f2bf(h.y); o.z = f2bf(h.z); o.w = f2bf(h.w);
    ((ushort4*)hv)[(size_t)(base + s) * 256 + ltid] = o;
  }
  ((float4*)carry)[(size_t)ch * 256 + ltid] = h;
}

// ---- the mega-kernel: prep | mid2 | gemm, separated by grid.sync -----------
// 256 blocks x 512 threads, cooperative. LDS = phase-3 buffers (132 KB),
// phases 1/2 alias into As. __threadfence on both sides of each grid.sync
// supplies the L2 writeback (release) / invalidate (acquire) that kernel
// boundaries used to provide (cross-XCD stale-line hazard on hv/Wc/Pbf).
__global__ __launch_bounds__(512) void mega(
    const float* __restrict__ x, const float* __restrict__ mask,
    const float* __restrict__ W_up, const float* __restrict__ b_up,
    const float* __restrict__ W_f, const float* __restrict__ bias_f,
    const float* __restrict__ dp,
    unsigned short* __restrict__ hv, float* __restrict__ carry,
    unsigned short* __restrict__ Wf_bf, unsigned short* __restrict__ WupT,
    unsigned short* __restrict__ Wc, unsigned short* __restrict__ Pbf,
    float* __restrict__ lbeta, float* __restrict__ cbeta,
    float* __restrict__ pbeta, float* __restrict__ bb,
    float* __restrict__ out) {
  __shared__ unsigned short As[2 * 256 * 64];   // 64 KB
  __shared__ unsigned short Bs[2 * 256 * 64];   // 64 KB
  __shared__ unsigned short Ps[2 * 16 * 64];    // 4 KB
  __shared__ float dpow[CHUNK];
  const int TSLOT = 256 * 64;
  const int PSLOT = 16 * 64;
  int tid = threadIdx.x;
  int blk = blockIdx.x;
  float decay = sigmoid_dev(dp);
  cg::grid_group grid = cg::this_grid();

  // ======================= phase 1: prep =======================
  {
    int g = tid >> 8;            // thread-group 0/1 (waves 0-3 / 4-7)
    int ltid = tid & 255;
    scan_chunk(blk * 4 + g * 2 + 0, ltid, decay, x, mask, hv, carry, lbeta, cbeta);
    scan_chunk(blk * 4 + g * 2 + 1, ltid, decay, x, mask, hv, carry, lbeta, cbeta);

    if (tid < 256) {
      // waves 0-3: one W_f row each -> bf16 + bb dot (full row, 4 passes)
      int w = tid >> 6, lane = tid & 63;
      int e = blk * 4 + w;
      const float4* row4 = (const float4*)(W_f + (size_t)e * DMODEL);
      const float4* bup4 = (const float4*)b_up;
      ushort4* out4 = (ushort4*)(Wf_bf + (size_t)e * DMODEL);
      float s = 0.f;
      #pragma unroll
      for (int q = 0; q < 4; ++q) {
        float4 v  = row4[q * 64 + lane];
        float4 bu = bup4[q * 64 + lane];
        ushort4 o;
        o.x = f2bf(v.x); o.y = f2bf(v.y); o.z = f2bf(v.z); o.w = f2bf(v.w);
        out4[q * 64 + lane] = o;
        s += v.x * bu.x + v.y * bu.y + v.z * bu.z + v.w * bu.w;
      }
      #pragma unroll
      for (int off = 32; off; off >>= 1) s += __shfl_down(s, off);
      if (lane == 0) bb[e] = s;
    } else {
      // waves 4-7: one 32x32 W_up transpose tile each (per-wave LDS region)
      int wv = (tid >> 6) - 4, lane = tid & 63;
      int id = blk * 4 + wv;
      int bx = id & 31, by = id >> 5;
      int x0c = bx * 32, y0 = by * 32;
      float* tw = (float*)As + wv * (32 * 33);
      #pragma unroll
      for (int p = 0; p < 4; ++p) {
        int idx = p * 64 + lane;           // 0..255
        int rr = idx >> 3, q = idx & 7;
        float4 t = *(const float4*)(W_up + (size_t)(y0 + rr) * DMODEL + x0c + q * 4);
        tw[rr * 33 + q * 4 + 0] = t.x;
        tw[rr * 33 + q * 4 + 1] = t.y;
        tw[rr * 33 + q * 4 + 2] = t.z;
        tw[rr * 33 + q * 4 + 3] = t.w;
      }
      asm volatile("s_waitcnt lgkmcnt(0)" ::: "memory");
      __builtin_amdgcn_sched_barrier(0);
      #pragma unroll
      for (int p = 0; p < 4; ++p) {
        int idx = p * 64 + lane;           // 0..255
        int d = idx >> 3, q = idx & 7;
        ushort4 o;
        o.x = f2bf(tw[(q * 4 + 0) * 33 + d]);
        o.y = f2bf(tw[(q * 4 + 1) * 33 + d]);
        o.z = f2bf(tw[(q * 4 + 2) * 33 + d]);
        o.w = f2bf(tw[(q * 4 + 3) * 33 + d]);
        *(ushort4*)(WupT + (size_t)(x0c + d) * DMODEL + y0 + q * 4) = o;
      }
    }
  }
  __syncthreads();
  __threadfence();          // release: WB dirty L2 lines
  grid.sync();
  __threadfence();          // acquire: INV stale L2 lines

  // ======================= phase 2: mid2 =======================
  {
    unsigned short* As2 = As;                  // 24 KB
    unsigned short* Bs2 = As + 3 * 4096;       // 24 KB (both inside As)
    if (tid < 256) {
      // waves 0-3: one Wc 64x64 tile per block (256 blocks = 16x16 tiles)
      int mt = blk >> 4, nt = blk & 15;
      f32x4 acc[2][2] = {};
      kloop64(Wf_bf, WupT, mt * 64, nt * 64, acc, As2, Bs2, tid);   // 16 barriers
      int lane = tid & 63, w = tid >> 6, wm = w & 1, wn = w >> 1;
      int quad = lane >> 4, l16 = lane & 15;
      #pragma unroll
      for (int j = 0; j < 2; ++j) {
        int col = nt * 64 + wn * 32 + j * 16 + l16;
        #pragma unroll
        for (int i = 0; i < 2; ++i) {
          int rowb = mt * 64 + wm * 32 + i * 16 + quad * 4;
          #pragma unroll
          for (int rr = 0; rr < 4; ++rr)
            Wc[(size_t)(rowb + rr) * DMODEL + col] = f2bf(acc[i][j][rr]);
        }
      }
    } else {
      float dL = powf(decay, (float)CHUNK);    // decay^16
      if (blk < 16) {
        // carry -> Pbf exclusive chunk scan; 16 echo barriers woven in
        int gid = blk * 256 + (tid - 256);     // 0..4095
        int b = gid >> 10, dd = gid & 1023;
        float P = 0.f;
        for (int c0 = 0; c0 < NCHUNK; c0 += 8) {
          float v[8];
          #pragma unroll
          for (int j = 0; j < 8; ++j)
            v[j] = carry[(size_t)(b * NCHUNK + c0 + j) * DMODEL + dd];
          #pragma unroll
          for (int j = 0; j < 8; ++j) {
            Pbf[(size_t)(b * NCHUNK + c0 + j) * DMODEL + dd] = f2bf(P);
            P = dL * P + v[j];
          }
          if (c0 & 8) __builtin_amdgcn_s_barrier();   // odd iters: 16 total
        }
      } else if (blk == 16) {
        // pbeta via shuffle scan (factor dL^4 per 4-chunk group); wave = batch
        int wv = (tid >> 6) - 4, lane = tid & 63;    // wv = batch b (0..3)
        float F = dL * dL; F = F * F;                // dL^4
        float c0v = cbeta[wv * NCHUNK + lane * 4 + 0];
        float c1v = cbeta[wv * NCHUNK + lane * 4 + 1];
        float c2v = cbeta[wv * NCHUNK + lane * 4 + 2];
        float c3v = cbeta[wv * NCHUNK + lane * 4 + 3];
        float p1 = c0v;
        float p2 = dL * p1 + c1v;
        float p3 = dL * p2 + c2v;
        float T  = dL * p3 + c3v;
        float s = T, f = F;
        #pragma unroll
        for (int off = 1; off < 64; off <<= 1) {
          float u = __shfl_up(s, off);
          if (lane >= off) s += f * u;
          f = f * f;
        }
        float E = __shfl_up(s, 1);
        if (lane == 0) E = 0.f;
        float q0 = E;
        float q1 = dL * q0 + c0v;
        float q2 = dL * q1 + c1v;
        float q3 = dL * q2 + c2v;
        pbeta[wv * NCHUNK + lane * 4 + 0] = q0;
        pbeta[wv * NCHUNK + lane * 4 + 1] = q1;
        pbeta[wv * NCHUNK + lane * 4 + 2] = q2;
        pbeta[wv * NCHUNK + lane * 4 + 3] = q3;
        for (int i = 0; i < 16; ++i) __builtin_amdgcn_s_barrier();
      } else {
        for (int i = 0; i < 16; ++i) __builtin_amdgcn_s_barrier();
      }
    }
  }
  __syncthreads();
  __threadfence();
  grid.sync();
  __threadfence();

  // ======================= phase 3: main GEMM (r9-verified body) ===========
  {
    if (tid < CHUNK) dpow[tid] = powf(decay, (float)(tid + 1));

    int lane = tid & 63, wid = tid >> 6;
    int wm = wid >> 2, wn = wid & 3;            // 2M x 4N waves
    int quad = lane >> 4, l16 = lane & 15;
    int r = tid >> 3, cch = tid & 7;            // staging: 64 rows x 8 chunks
    int g = cch ^ (r & 7);                      // pre-swizzled global chunk

    int xcd = blk & 7, jb = blk >> 3;
    int m0 = (xcd * 8 + (jb >> 2)) * 256;       // 64 m-tiles
    int n0 = (jb & 3) * 256;                    // 4 n-tiles
    int chunk0 = m0 >> 4;                       // first of this block's 16 chunks

    f32x4 acc[8][4] = {};
    f32x4 Pacc[4] = {};

    auto stageT = [&](int t, int p) {
      int k0 = t * 64;
      unsigned short* dA = As + p * TSLOT;
      unsigned short* dB = Bs + p * TSLOT;
      #pragma unroll
      for (int q = 0; q < 4; ++q)
        gl2lds16(hv + (size_t)(m0 + q * 64 + r) * DMODEL + k0 + g * 8,
                 dA + (q * 64 + r) * 64 + cch * 8);
      #pragma unroll
      for (int q = 0; q < 4; ++q)
        gl2lds16(Wc + (size_t)(n0 + q * 64 + r) * DMODEL + k0 + g * 8,
                 dB + (q * 64 + r) * 64 + cch * 8);
      if (wid < 2) {
        int rp = wid * 8 + (lane >> 3), cp = lane & 7;
        int gp = cp ^ (rp & 7);
        gl2lds16(Pbf + (size_t)(chunk0 + rp) * DMODEL + k0 + gp * 8,
                 Ps + p * PSLOT + (wid * 64 + lane) * 8);
      }
    };
    auto compute = [&](int p) {
      const bf16x8* Av = (const bf16x8*)(As + p * TSLOT);
      const bf16x8* Bv = (const bf16x8*)(Bs + p * TSLOT);
      const bf16x8* Pv = (const bf16x8*)(Ps + p * PSLOT);
      #pragma unroll
      for (int kk = 0; kk < 2; ++kk) {
        bf16x8 bfr[4];
        #pragma unroll
        for (int j = 0; j < 4; ++j) {
          int rowB = wn * 64 + j * 16 + l16;
          bfr[j] = Bv[rowB * 8 + ((kk * 4 + quad) ^ (l16 & 7))];
        }
        bf16x8 pf = Pv[l16 * 8 + ((kk * 4 + quad) ^ (l16 & 7))];
        __builtin_amdgcn_s_setprio(1);
        #pragma unroll
        for (int j = 0; j < 4; ++j)
          Pacc[j] = __builtin_amdgcn_mfma_f32_16x16x32_bf16(pf, bfr[j], Pacc[j], 0, 0, 0);
        __builtin_amdgcn_s_setprio(0);
        #pragma unroll
        for (int i = 0; i < 8; ++i) {
          int rowA = wm * 128 + i * 16 + l16;
          bf16x8 af = Av[rowA * 8 + ((kk * 4 + quad) ^ (l16 & 7))];
          __builtin_amdgcn_s_setprio(1);
          #pragma unroll
          for (int j = 0; j < 4; ++j)
            acc[i][j] = __builtin_amdgcn_mfma_f32_16x16x32_bf16(af, bfr[j], acc[i][j], 0, 0, 0);
          __builtin_amdgcn_s_setprio(0);
        }
      }
    };

    stageT(0, 0);
    __syncthreads();

    for (int t = 0; t < 15; ++t) {
      int p = t & 1;
      stageT(t + 1, p ^ 1);
      compute(p);
      asm volatile("s_waitcnt vmcnt(0)" ::: "memory");
      __builtin_amdgcn_s_barrier();
      asm volatile("" ::: "memory");
    }
    compute(1);                                 // tile 15 (buf 1)

    // Fused Pout publish: 16x256 f32 via LDS (As buf0; disjoint from buf1).
    float* Plds = (float*)As;                   // [16][256] f32 = 16 KB
    if (wm == 0) {
      #pragma unroll
      for (int j = 0; j < 4; ++j)
        #pragma unroll
        for (int rr = 0; rr < 4; ++rr)
          Plds[(quad * 4 + rr) * 256 + wn * 64 + j * 16 + l16] = Pacc[j][rr];
    }
    __syncthreads();

    float bbv[4], bfv[4];
    #pragma unroll
    for (int j = 0; j < 4; ++j) {
      int col = n0 + wn * 64 + j * 16 + l16;
      bbv[j] = bb[col];
      bfv[j] = bias_f[col];
    }
    #pragma unroll
    for (int i = 0; i < 8; ++i) {
      int chl = wm * 8 + i;                     // fragment i = one chunk
      float pb = pbeta[chunk0 + chl];
      #pragma unroll
      for (int rr = 0; rr < 4; ++rr) {
        int row = m0 + wm * 128 + i * 16 + quad * 4 + rr;
        float lb  = lbeta[row];
        float dpw = dpow[row & (CHUNK - 1)];
        float* outRow = out + (size_t)row * DMODEL;
        #pragma unroll
        for (int j = 0; j < 4; ++j) {
          int col = n0 + wn * 64 + j * 16 + l16;
          float po = Plds[chl * 256 + wn * 64 + j * 16 + l16] + pb * bbv[j];
          outRow[col] = acc[i][j][rr] + dpw * po + lb * bbv[j] + bfv[j];
        }
      }
    }
  }
}

// ---- launch ----------------------------------------------------------------

extern "C" void kernel_launch(void* const* d_in, const int* in_sizes, int n_in,
                              void* d_out, int out_size, void* d_ws, size_t ws_size,
                              hipStream_t stream) {
  const float* x    = (const float*)d_in[0];
  const float* mask = (const float*)d_in[1];
  const float* W_up = (const float*)d_in[2];
  const float* b_up = (const float*)d_in[3];
  const float* W_f  = (const float*)d_in[4];
  const float* b_f  = (const float*)d_in[5];
  const float* dp   = (const float*)d_in[6];
  float* out = (float*)d_out;

  char* ws = (char*)d_ws;
  unsigned short* hv    = (unsigned short*)(ws);                 // 32 MB
  unsigned short* Wc    = (unsigned short*)(ws + 33554432);      // 2 MB
  unsigned short* Wf_bf = (unsigned short*)(ws + 35651584);      // 2 MB
  unsigned short* WupT  = (unsigned short*)(ws + 37748736);      // 2 MB
  float* carry  = (float*)(ws + 39845888);                       // 4 MB (1024x1024 f32)
  unsigned short* Pbf = (unsigned short*)(ws + 44040192);        // 2 MB (1024x1024 bf16)
  float* lbeta  = (float*)(ws + 46137344);                       // 64 KB
  float* cbeta  = (float*)(ws + 46202880);                       // 4 KB
  float* pbeta  = (float*)(ws + 46206976);                       // 4 KB
  float* bb     = (float*)(ws + 46211072);                       // 4 KB

  void* kargs[] = {
    (void*)&x, (void*)&mask, (void*)&W_up, (void*)&b_up, (void*)&W_f,
    (void*)&b_f, (void*)&dp,
    (void*)&hv, (void*)&carry, (void*)&Wf_bf, (void*)&WupT, (void*)&Wc,
    (void*)&Pbf, (void*)&lbeta, (void*)&cbeta, (void*)&pbeta, (void*)&bb,
    (void*)&out
  };
  hipLaunchCooperativeKernel((const void*)mega, dim3(256), dim3(512),
                             kargs, 0, stream);
}